// Round 1
// baseline (403.220 us; speedup 1.0000x reference)
//
#include <hip/hip_runtime.h>
#include <hip/hip_bf16.h>
#include <cstdint>
#include <cstddef>

typedef __bf16 bf16_t;
typedef __bf16 bf16x8 __attribute__((ext_vector_type(8)));
typedef float  f32x4  __attribute__((ext_vector_type(4)));

constexpr int kBatch = 4;
constexpr int kT = 4096;
constexpr int kD = 1024;
constexpr int kM = kBatch * kT;     // 16384 rows
constexpr int kCH = kBatch * kD;    // 4096 scan channels
constexpr int kNC = 128;            // scan chunks
constexpr int kL  = kT / kNC;       // 32 steps per chunk

// ---------------------------------------------------------------- helpers
__device__ __forceinline__ void async16(const void* g, void* l) {
    __builtin_amdgcn_global_load_lds(
        (const __attribute__((address_space(1))) uint32_t*)g,
        (__attribute__((address_space(3))) uint32_t*)l,
        16, 0, 0);
}

// ---------------------------------------------------------------- f32 -> bf16 cast (8 elems/thread)
__global__ void cvt_bf16_kernel(const float* __restrict__ in, bf16_t* __restrict__ out, int n8) {
    int i = blockIdx.x * blockDim.x + threadIdx.x;
    if (i >= n8) return;
    const float4* p = reinterpret_cast<const float4*>(in) + 2 * (size_t)i;
    float4 a = p[0], b = p[1];
    bf16x8 o;
    o[0] = (bf16_t)a.x; o[1] = (bf16_t)a.y; o[2] = (bf16_t)a.z; o[3] = (bf16_t)a.w;
    o[4] = (bf16_t)b.x; o[5] = (bf16_t)b.y; o[6] = (bf16_t)b.z; o[7] = (bf16_t)b.w;
    *reinterpret_cast<bf16x8*>(out + 8 * (size_t)i) = o;
}

// ---------------------------------------------------------------- GEMM: C[m][n] = sum_k A[m][k]*Bw[n][k]
// m97 structure: 128x128 tile, BK=64, 4 waves (2x2), 16x16x32 bf16 MFMA,
// global_load_lds width 16, single-buffered LDS.
// EPI: 0 = silu -> bf16 | 1 = sigmoid(acc+bias[n]) -> f32
//      2 = aux[idx]*tanh(acc+bias[n]) -> f32 | 3 = plain f32
template<int EPI>
__global__ __launch_bounds__(256)
void gemm_bt(const bf16_t* __restrict__ A, const bf16_t* __restrict__ Bw,
             const float* __restrict__ bias, const float* __restrict__ aux,
             void* __restrict__ outp, int M, int N, int K)
{
    __shared__ __align__(16) bf16_t lA[128 * 64];
    __shared__ __align__(16) bf16_t lB[128 * 64];
    const int tid  = threadIdx.x;
    const int w    = tid >> 6;
    const int lane = tid & 63;
    const int wr   = (w >> 1) * 64;   // wave row offset in tile
    const int wc   = (w & 1) * 64;    // wave col offset in tile
    const int m0   = blockIdx.y * 128;
    const int n0   = blockIdx.x * 128;
    const int l16  = lane & 15;
    const int lhi  = lane >> 4;

    f32x4 acc[4][4];
#pragma unroll
    for (int i = 0; i < 4; ++i)
#pragma unroll
        for (int j = 0; j < 4; ++j)
            acc[i][j] = (f32x4){0.f, 0.f, 0.f, 0.f};

    for (int k0 = 0; k0 < K; k0 += 64) {
        // ---- stage A/B tiles (each 128 rows x 64 bf16 = 16KB) ----
#pragma unroll
        for (int r = 0; r < 4; ++r) {
            const int ci  = r * 256 + tid;        // 16B chunk index 0..1023
            const int row = ci >> 3;              // 8 chunks per 128B row
            const int col = (ci & 7) << 3;        // bf16 col
            async16(A  + (size_t)(m0 + row) * K + (k0 + col),
                    (char*)lA + (size_t)(r * 256 + w * 64) * 16);
            async16(Bw + (size_t)(n0 + row) * K + (k0 + col),
                    (char*)lB + (size_t)(r * 256 + w * 64) * 16);
        }
        __syncthreads();
        // ---- compute: 2 k-steps of 32 ----
#pragma unroll
        for (int ks = 0; ks < 2; ++ks) {
            const int kb = ks * 32 + lhi * 8;
            bf16x8 aF[4], bF[4];
#pragma unroll
            for (int i = 0; i < 4; ++i)
                aF[i] = *reinterpret_cast<const bf16x8*>(&lA[(size_t)(wr + i * 16 + l16) * 64 + kb]);
#pragma unroll
            for (int j = 0; j < 4; ++j)
                bF[j] = *reinterpret_cast<const bf16x8*>(&lB[(size_t)(wc + j * 16 + l16) * 64 + kb]);
#pragma unroll
            for (int i = 0; i < 4; ++i)
#pragma unroll
                for (int j = 0; j < 4; ++j)
                    acc[i][j] = __builtin_amdgcn_mfma_f32_16x16x32_bf16(aF[i], bF[j], acc[i][j], 0, 0, 0);
        }
        __syncthreads();
    }

    // ---- epilogue: C/D layout col=lane&15, row=(lane>>4)*4+r (m89/m91-verified) ----
#pragma unroll
    for (int i = 0; i < 4; ++i) {
#pragma unroll
        for (int j = 0; j < 4; ++j) {
            const int colg = n0 + wc + j * 16 + l16;
            float bs = 0.f;
            if constexpr (EPI == 1 || EPI == 2) bs = bias[colg];
#pragma unroll
            for (int r = 0; r < 4; ++r) {
                const int rowg = m0 + wr + i * 16 + lhi * 4 + r;
                const size_t idx = (size_t)rowg * N + colg;
                const float f = acc[i][j][r];
                if constexpr (EPI == 0) {
                    float s = f / (1.f + __expf(-f));
                    reinterpret_cast<bf16_t*>(outp)[idx] = (bf16_t)s;
                } else if constexpr (EPI == 1) {
                    reinterpret_cast<float*>(outp)[idx] = 1.f / (1.f + __expf(-(f + bs)));
                } else if constexpr (EPI == 2) {
                    reinterpret_cast<float*>(outp)[idx] = aux[idx] * tanhf(f + bs);
                } else {
                    reinterpret_cast<float*>(outp)[idx] = f;
                }
            }
        }
    }
}

// ---------------------------------------------------------------- chunked linear scan
// h_t = a_t*h + bv_t  over T, per channel (b,d). Chunk aggregates: h_out = A*h_in + B.
__global__ void scan_chunk_kernel(const float* __restrict__ alpha,
                                  const float* __restrict__ bv,
                                  float* __restrict__ Aagg,
                                  float* __restrict__ Bagg)
{
    const int u  = blockIdx.x * blockDim.x + threadIdx.x;  // [0, kNC*kCH)
    const int ch = u & (kCH - 1);
    const int c  = u >> 12;           // kCH = 4096
    const int b  = ch >> 10;          // kD = 1024
    const int d  = ch & (kD - 1);
    size_t base = ((size_t)b * kT + (size_t)c * kL) * kD + d;
    float Ac = 1.f, Bc = 0.f;
#pragma unroll 4
    for (int t = 0; t < kL; ++t) {
        float a = alpha[base];
        float v = bv[base];
        Ac *= a;
        Bc = a * Bc + v;
        base += kD;
    }
    Aagg[u] = Ac;
    Bagg[u] = Bc;
}

__global__ void scan_mid_kernel(const float* __restrict__ Aagg,
                                const float* __restrict__ Bagg,
                                float* __restrict__ Hin,
                                float* __restrict__ hlast)
{
    const int ch = blockIdx.x * blockDim.x + threadIdx.x;  // [0, kCH)
    float h = 0.f;
#pragma unroll 8
    for (int c = 0; c < kNC; ++c) {
        Hin[(size_t)c * kCH + ch] = h;
        h = Aagg[(size_t)c * kCH + ch] * h + Bagg[(size_t)c * kCH + ch];
    }
    hlast[ch] = h;  // h_last output (fp32)
}

__global__ void scan_out_kernel(const float* __restrict__ alpha,
                                const float* __restrict__ bv,
                                const float* __restrict__ Hin,
                                bf16_t* __restrict__ cell)
{
    const int u  = blockIdx.x * blockDim.x + threadIdx.x;
    const int ch = u & (kCH - 1);
    const int c  = u >> 12;
    const int b  = ch >> 10;
    const int d  = ch & (kD - 1);
    size_t base = ((size_t)b * kT + (size_t)c * kL) * kD + d;
    float h = Hin[u];
#pragma unroll 4
    for (int t = 0; t < kL; ++t) {
        float a = alpha[base];
        float v = bv[base];
        h = a * h + v;
        float s = 1.f / (1.f + __expf(-h));     // sigmoid(h)
        cell[base] = (bf16_t)(h * h * s);       // h * silu(h)
        base += kD;
    }
}

// ---------------------------------------------------------------- launch
extern "C" void kernel_launch(void* const* d_in, const int* in_sizes, int n_in,
                              void* d_out, int out_size, void* d_ws, size_t ws_size,
                              hipStream_t stream)
{
    const float* x     = (const float*)d_in[0];
    const float* W_in  = (const float*)d_in[1];
    const float* W_al  = (const float*)d_in[2];
    const float* b_al  = (const float*)d_in[3];
    const float* W_be  = (const float*)d_in[4];
    const float* b_be  = (const float*)d_in[5];
    const float* W_v   = (const float*)d_in[6];
    const float* b_v   = (const float*)d_in[7];
    const float* W_out = (const float*)d_in[8];

    float* out   = (float*)d_out;
    float* hlast = out + (size_t)kM * kD;

    // workspace layout (~203 MB)
    char* ws = (char*)d_ws;
    size_t off = 0;
    auto alloc = [&](size_t bytes) -> void* {
        void* p = ws + off;
        off += (bytes + 255) & ~(size_t)255;
        return p;
    };
    bf16_t* xbf   = (bf16_t*)alloc((size_t)kM * kD * 2);   // later reused as cell
    bf16_t* xp    = (bf16_t*)alloc((size_t)kM * kD * 2);   // later reused for scan aggregates
    float*  alpha = (float*) alloc((size_t)kM * kD * 4);
    float*  bvb   = (float*) alloc((size_t)kM * kD * 4);   // beta_s, then bv in place
    bf16_t* wbf   = (bf16_t*)alloc((size_t)5 * kD * kD * 2);

    bf16_t* Winb = wbf;
    bf16_t* Walb = wbf + 1 * (size_t)kD * kD;
    bf16_t* Wbeb = wbf + 2 * (size_t)kD * kD;
    bf16_t* Wvb  = wbf + 3 * (size_t)kD * kD;
    bf16_t* Wob  = wbf + 4 * (size_t)kD * kD;

    bf16_t* cell = xbf;                  // overlay: xbf dead after GEMM1
    float*  Aagg = (float*)xp;           // overlay: xp dead after GEMM4
    float*  Bagg = Aagg + (size_t)kNC * kCH;
    float*  Hin  = Bagg + (size_t)kNC * kCH;

    // 1) casts to bf16
    {
        int n8 = kM * kD / 8;
        cvt_bf16_kernel<<<(n8 + 255) / 256, 256, 0, stream>>>(x, xbf, n8);
        int w8 = kD * kD / 8;
        int wg = (w8 + 255) / 256;
        cvt_bf16_kernel<<<wg, 256, 0, stream>>>(W_in,  Winb, w8);
        cvt_bf16_kernel<<<wg, 256, 0, stream>>>(W_al,  Walb, w8);
        cvt_bf16_kernel<<<wg, 256, 0, stream>>>(W_be,  Wbeb, w8);
        cvt_bf16_kernel<<<wg, 256, 0, stream>>>(W_v,   Wvb,  w8);
        cvt_bf16_kernel<<<wg, 256, 0, stream>>>(W_out, Wob,  w8);
    }

    dim3 grid(kD / 128, kM / 128);   // (8, 128)

    // 2) xp = silu(x @ W_in^T)              [bf16]
    gemm_bt<0><<<grid, 256, 0, stream>>>(xbf, Winb, nullptr, nullptr, xp, kM, kD, kD);
    // 3) alpha = sigmoid(xp @ W_a^T + b_a)  [f32]
    gemm_bt<1><<<grid, 256, 0, stream>>>(xp, Walb, b_al, nullptr, alpha, kM, kD, kD);
    //    beta  = sigmoid(xp @ W_b^T + b_b)  [f32] (into bvb)
    gemm_bt<1><<<grid, 256, 0, stream>>>(xp, Wbeb, b_be, nullptr, bvb, kM, kD, kD);
    //    bv    = beta * tanh(xp @ W_v^T + b_v)  [f32, in place over beta]
    gemm_bt<2><<<grid, 256, 0, stream>>>(xp, Wvb, b_v, bvb, bvb, kM, kD, kD);

    // 4) chunked scan
    scan_chunk_kernel<<<kNC * kCH / 256, 256, 0, stream>>>(alpha, bvb, Aagg, Bagg);
    scan_mid_kernel<<<kCH / 256, 256, 0, stream>>>(Aagg, Bagg, Hin, hlast);
    scan_out_kernel<<<kNC * kCH / 256, 256, 0, stream>>>(alpha, bvb, Hin, cell);

    // 5) output = cell @ W_out^T            [f32 -> d_out]
    gemm_bt<3><<<grid, 256, 0, stream>>>(cell, Wob, nullptr, nullptr, out, kM, kD, kD);
}

// Round 2
// 349.449 us; speedup vs baseline: 1.1539x; 1.1539x over previous
//
#include <hip/hip_runtime.h>
#include <hip/hip_bf16.h>
#include <cstdint>
#include <cstddef>

typedef __bf16 bf16_t;
typedef __bf16 bf16x8 __attribute__((ext_vector_type(8)));
typedef float  f32x4  __attribute__((ext_vector_type(4)));

constexpr int kBatch = 4;
constexpr int kT = 4096;
constexpr int kD = 1024;
constexpr int kM = kBatch * kT;     // 16384 rows
constexpr int kCH = kBatch * kD;    // 4096 scan channels
constexpr int kNC = 128;            // scan chunks
constexpr int kL  = kT / kNC;       // 32 steps per chunk
constexpr int LDS_BYTES = 131072;   // 2 bufs x (A 32K + B 32K)

// ---------------------------------------------------------------- helpers
__device__ __forceinline__ void async16(const bf16_t* g, char* l) {
    __builtin_amdgcn_global_load_lds(
        (const __attribute__((address_space(1))) uint32_t*)g,
        (__attribute__((address_space(3))) uint32_t*)l,
        16, 0, 0);
}

// ---------------------------------------------------------------- f32 -> bf16 cast
__global__ void cvt_bf16_kernel(const float* __restrict__ in, bf16_t* __restrict__ out, int n8) {
    int i = blockIdx.x * blockDim.x + threadIdx.x;
    if (i >= n8) return;
    const float4* p = reinterpret_cast<const float4*>(in) + 2 * (size_t)i;
    float4 a = p[0], b = p[1];
    bf16x8 o;
    o[0] = (bf16_t)a.x; o[1] = (bf16_t)a.y; o[2] = (bf16_t)a.z; o[3] = (bf16_t)a.w;
    o[4] = (bf16_t)b.x; o[5] = (bf16_t)b.y; o[6] = (bf16_t)b.z; o[7] = (bf16_t)b.w;
    *reinterpret_cast<bf16x8*>(out + 8 * (size_t)i) = o;
}

// ---------------------------------------------------------------- 256x256 8-phase GEMM
// C[m][n] = sum_k A[m][k]*Bw[n][k].  BM=BN=256, BK=64, 8 waves (2M x 4N),
// per-wave 128x64 out. LDS: 2 bufs x {A[2 halves][128][64], B[2][128][64]} bf16,
// 16x32-subtiled with st_16x32 XOR swizzle (byte^=((byte>>9)&1)<<5), applied via
// pre-swizzled GLOBAL source (gload_lds dest stays linear) + swizzled ds_read.
// Schedule: 4 phases/K-tile; quadrants Q0=(Alo,Blo) Q1=(Alo,Bhi) Q2=(Ahi,Blo)
// Q3=(Ahi,Bhi). Stages: P1:Blo(w+1) P2:Alo(w+2) P3:Bhi(w+2) P4:Ahi(w+2).
// vmcnt(6) at P4 only (3 half-tiles in flight), drain vmcnt(0) at w==NT-2.
// EPI: 0 silu->bf16 | 1 sigmoid(+bias)->f32 | 2 aux*tanh(+bias)->f32 | 3 f32
template<int EPI>
__global__ __launch_bounds__(512, 2)
void gemm256(const bf16_t* __restrict__ A, const bf16_t* __restrict__ Bw,
             const float* __restrict__ bias, const float* __restrict__ aux,
             void* __restrict__ outp, int M, int N, int K)
{
    extern __shared__ char lds[];
    const int tid  = threadIdx.x;
    const int lane = tid & 63;
    const int wv   = tid >> 6;
    const int wr   = wv >> 2;      // 0..1  (M waves)
    const int wc   = wv & 3;       // 0..3  (N waves)
    const int l16  = lane & 15;
    const int lhi  = lane >> 4;

    // ---- bijective XCD-chunk swizzle (nwg % 8 == 0 here: 256) ----
    int bid = blockIdx.y * gridDim.x + blockIdx.x;
    int nwg = gridDim.x * gridDim.y;
    int swz = (bid & 7) * (nwg >> 3) + (bid >> 3);
    int gx  = N >> 8;
    int n0  = (swz % gx) << 8;
    int m0  = (swz / gx) << 8;

    // ---- staging per-thread constants (inverse-swizzled global offsets) ----
    auto goff = [&](int chunk) -> size_t {
        int st = chunk >> 6;               // 1KB subtile
        int ri = (chunk >> 2) & 15;        // inner row
        int cp = (chunk & 3) << 3;         // physical inner col (bf16)
        int cl = cp ^ (((ri >> 3) & 1) << 4);  // logical col (involution)
        int gr = ((st >> 1) << 4) + ri;    // row within 128-row half
        int gc = ((st & 1) << 5) + cl;     // col within BK=64
        return (size_t)gr * K + gc;
    };
    const size_t g0 = goff(tid), g1 = goff(512 + tid);
    const int d0 = wv << 10, d1 = 8192 + (wv << 10);   // linear LDS dest (wave base)

    auto STAGE = [&](const bf16_t* G, int row0, int k0, int lds_base) {
        const bf16_t* base = G + (size_t)row0 * K + k0;
        async16(base + g0, lds + lds_base + d0);
        async16(base + g1, lds + lds_base + d1);
    };

    // ---- swizzled ds_read offsets (relative to a half-region base) ----
    auto ldsoff = [&](int r, int c) -> int {
        int ri = r & 15;
        int st = ((r >> 4) << 1) | (c >> 5);
        int cw = (c & 31) ^ (((ri >> 3) & 1) << 4);
        return (st << 10) + (ri << 6) + (cw << 1);
    };
    int offA[4][2], offB[2][2];
#pragma unroll
    for (int m = 0; m < 4; ++m)
#pragma unroll
        for (int s = 0; s < 2; ++s)
            offA[m][s] = ldsoff(wr * 64 + m * 16 + l16, s * 32 + lhi * 8);
#pragma unroll
    for (int n = 0; n < 2; ++n)
#pragma unroll
        for (int s = 0; s < 2; ++s)
            offB[n][s] = ldsoff(wc * 32 + n * 16 + l16, s * 32 + lhi * 8);

    f32x4 acc[8][4];
#pragma unroll
    for (int i = 0; i < 8; ++i)
#pragma unroll
        for (int j = 0; j < 4; ++j)
            acc[i][j] = (f32x4){0.f, 0.f, 0.f, 0.f};

    const int NT = K >> 6;   // 16

    // LDS region byte offsets: A[buf][h] = buf*65536 + h*16384
    //                          B[buf][h] = buf*65536 + 32768 + h*16384
    // ---- prologue: tile0 all 4 halves, then tile1 {Alo, Bhi, Ahi} ----
    STAGE(A,  m0,        0, 0);
    STAGE(A,  m0 + 128,  0, 16384);
    STAGE(Bw, n0,        0, 32768);
    STAGE(Bw, n0 + 128,  0, 49152);
    STAGE(A,  m0,       64, 65536);
    STAGE(Bw, n0 + 128, 64, 65536 + 49152);
    STAGE(A,  m0 + 128, 64, 65536 + 16384);
    asm volatile("s_waitcnt vmcnt(6)" ::: "memory");
    asm volatile("s_barrier" ::: "memory");

    for (int w = 0; w < NT; ++w) {
        const int bufo  = (w & 1) << 16;
        const int nbufo = bufo ^ 65536;
        const int oA0 = bufo, oA1 = bufo + 16384;
        const int oB0 = bufo + 32768, oB1 = bufo + 49152;
        const int k1 = (w + 1) << 6, k2 = (w + 2) << 6;
        bf16x8 aL[4][2], aH[4][2], bL[2][2], bH[2][2];

        // ===== P1: read Alo,Blo ; stage Blo(w+1) ; Q0 =====
#pragma unroll
        for (int m = 0; m < 4; ++m)
#pragma unroll
            for (int s = 0; s < 2; ++s)
                aL[m][s] = *reinterpret_cast<const bf16x8*>(lds + oA0 + offA[m][s]);
#pragma unroll
        for (int n = 0; n < 2; ++n)
#pragma unroll
            for (int s = 0; s < 2; ++s)
                bL[n][s] = *reinterpret_cast<const bf16x8*>(lds + oB0 + offB[n][s]);
        if (w + 1 < NT) STAGE(Bw, n0, k1, nbufo + 32768);
        asm volatile("s_barrier" ::: "memory");
        __builtin_amdgcn_s_setprio(1);
#pragma unroll
        for (int m = 0; m < 4; ++m)
#pragma unroll
            for (int n = 0; n < 2; ++n)
#pragma unroll
                for (int s = 0; s < 2; ++s)
                    acc[m][n] = __builtin_amdgcn_mfma_f32_16x16x32_bf16(aL[m][s], bL[n][s], acc[m][n], 0, 0, 0);
        __builtin_amdgcn_s_setprio(0);
        asm volatile("s_barrier" ::: "memory");

        // ===== P2: read Bhi ; stage Alo(w+2) ; Q1 =====
#pragma unroll
        for (int n = 0; n < 2; ++n)
#pragma unroll
            for (int s = 0; s < 2; ++s)
                bH[n][s] = *reinterpret_cast<const bf16x8*>(lds + oB1 + offB[n][s]);
        if (w + 2 < NT) STAGE(A, m0, k2, oA0);
        asm volatile("s_barrier" ::: "memory");
        __builtin_amdgcn_s_setprio(1);
#pragma unroll
        for (int m = 0; m < 4; ++m)
#pragma unroll
            for (int n = 0; n < 2; ++n)
#pragma unroll
                for (int s = 0; s < 2; ++s)
                    acc[m][2 + n] = __builtin_amdgcn_mfma_f32_16x16x32_bf16(aL[m][s], bH[n][s], acc[m][2 + n], 0, 0, 0);
        __builtin_amdgcn_s_setprio(0);
        asm volatile("s_barrier" ::: "memory");

        // ===== P3: read Ahi ; stage Bhi(w+2) ; Q2 =====
#pragma unroll
        for (int m = 0; m < 4; ++m)
#pragma unroll
            for (int s = 0; s < 2; ++s)
                aH[m][s] = *reinterpret_cast<const bf16x8*>(lds + oA1 + offA[m][s]);
        if (w + 2 < NT) STAGE(Bw, n0 + 128, k2, oB1);
        asm volatile("s_barrier" ::: "memory");
        __builtin_amdgcn_s_setprio(1);
#pragma unroll
        for (int m = 0; m < 4; ++m)
#pragma unroll
            for (int n = 0; n < 2; ++n)
#pragma unroll
                for (int s = 0; s < 2; ++s)
                    acc[4 + m][n] = __builtin_amdgcn_mfma_f32_16x16x32_bf16(aH[m][s], bL[n][s], acc[4 + m][n], 0, 0, 0);
        __builtin_amdgcn_s_setprio(0);
        asm volatile("s_barrier" ::: "memory");

        // ===== P4: stage Ahi(w+2) ; Q3 ; counted vmcnt ; barrier =====
        if (w + 2 < NT) STAGE(A, m0 + 128, k2, oA1);
        asm volatile("s_barrier" ::: "memory");
        __builtin_amdgcn_s_setprio(1);
#pragma unroll
        for (int m = 0; m < 4; ++m)
#pragma unroll
            for (int n = 0; n < 2; ++n)
#pragma unroll
                for (int s = 0; s < 2; ++s)
                    acc[4 + m][2 + n] = __builtin_amdgcn_mfma_f32_16x16x32_bf16(aH[m][s], bH[n][s], acc[4 + m][2 + n], 0, 0, 0);
        __builtin_amdgcn_s_setprio(0);
        if (w + 2 < NT) {
            asm volatile("s_waitcnt vmcnt(6)" ::: "memory");
        } else if (w + 2 == NT) {
            asm volatile("s_waitcnt vmcnt(0)" ::: "memory");
        }
        if (w + 1 < NT) asm volatile("s_barrier" ::: "memory");
    }

    // ---- epilogue: C/D layout col=lane&15, row=(lane>>4)*4+r ----
#pragma unroll
    for (int j = 0; j < 4; ++j) {
        const int colg = n0 + ((j >> 1) << 7) + wc * 32 + (j & 1) * 16 + l16;
        float bs = 0.f;
        if constexpr (EPI == 1 || EPI == 2) bs = bias[colg];
#pragma unroll
        for (int i = 0; i < 8; ++i) {
            const int rb = m0 + ((i >> 2) << 7) + wr * 64 + (i & 3) * 16 + lhi * 4;
#pragma unroll
            for (int r = 0; r < 4; ++r) {
                const size_t idx = (size_t)(rb + r) * N + colg;
                const float f = acc[i][j][r];
                if constexpr (EPI == 0) {
                    float s = f / (1.f + __expf(-f));
                    reinterpret_cast<bf16_t*>(outp)[idx] = (bf16_t)s;
                } else if constexpr (EPI == 1) {
                    reinterpret_cast<float*>(outp)[idx] = 1.f / (1.f + __expf(-(f + bs)));
                } else if constexpr (EPI == 2) {
                    reinterpret_cast<float*>(outp)[idx] = aux[idx] * tanhf(f + bs);
                } else {
                    reinterpret_cast<float*>(outp)[idx] = f;
                }
            }
        }
    }
}

// ---------------------------------------------------------------- chunked linear scan
__global__ void scan_chunk_kernel(const float* __restrict__ alpha,
                                  const float* __restrict__ bv,
                                  float* __restrict__ Aagg,
                                  float* __restrict__ Bagg)
{
    const int u  = blockIdx.x * blockDim.x + threadIdx.x;
    const int ch = u & (kCH - 1);
    const int c  = u >> 12;
    const int b  = ch >> 10;
    const int d  = ch & (kD - 1);
    size_t base = ((size_t)b * kT + (size_t)c * kL) * kD + d;
    float Ac = 1.f, Bc = 0.f;
#pragma unroll 4
    for (int t = 0; t < kL; ++t) {
        float a = alpha[base];
        float v = bv[base];
        Ac *= a;
        Bc = a * Bc + v;
        base += kD;
    }
    Aagg[u] = Ac;
    Bagg[u] = Bc;
}

__global__ void scan_mid_kernel(const float* __restrict__ Aagg,
                                const float* __restrict__ Bagg,
                                float* __restrict__ Hin,
                                float* __restrict__ hlast)
{
    const int ch = blockIdx.x * blockDim.x + threadIdx.x;
    float h = 0.f;
#pragma unroll 8
    for (int c = 0; c < kNC; ++c) {
        Hin[(size_t)c * kCH + ch] = h;
        h = Aagg[(size_t)c * kCH + ch] * h + Bagg[(size_t)c * kCH + ch];
    }
    hlast[ch] = h;
}

__global__ void scan_out_kernel(const float* __restrict__ alpha,
                                const float* __restrict__ bv,
                                const float* __restrict__ Hin,
                                bf16_t* __restrict__ cell)
{
    const int u  = blockIdx.x * blockDim.x + threadIdx.x;
    const int ch = u & (kCH - 1);
    const int c  = u >> 12;
    const int b  = ch >> 10;
    const int d  = ch & (kD - 1);
    size_t base = ((size_t)b * kT + (size_t)c * kL) * kD + d;
    float h = Hin[u];
#pragma unroll 4
    for (int t = 0; t < kL; ++t) {
        float a = alpha[base];
        float v = bv[base];
        h = a * h + v;
        float s = 1.f / (1.f + __expf(-h));
        cell[base] = (bf16_t)(h * h * s);
        base += kD;
    }
}

// ---------------------------------------------------------------- launch
extern "C" void kernel_launch(void* const* d_in, const int* in_sizes, int n_in,
                              void* d_out, int out_size, void* d_ws, size_t ws_size,
                              hipStream_t stream)
{
    const float* x     = (const float*)d_in[0];
    const float* W_in  = (const float*)d_in[1];
    const float* W_al  = (const float*)d_in[2];
    const float* b_al  = (const float*)d_in[3];
    const float* W_be  = (const float*)d_in[4];
    const float* b_be  = (const float*)d_in[5];
    const float* W_v   = (const float*)d_in[6];
    const float* b_v   = (const float*)d_in[7];
    const float* W_out = (const float*)d_in[8];

    float* out   = (float*)d_out;
    float* hlast = out + (size_t)kM * kD;

    char* ws = (char*)d_ws;
    size_t off = 0;
    auto alloc = [&](size_t bytes) -> void* {
        void* p = ws + off;
        off += (bytes + 255) & ~(size_t)255;
        return p;
    };
    bf16_t* xbf   = (bf16_t*)alloc((size_t)kM * kD * 2);
    bf16_t* xp    = (bf16_t*)alloc((size_t)kM * kD * 2);
    float*  alpha = (float*) alloc((size_t)kM * kD * 4);
    float*  bvb   = (float*) alloc((size_t)kM * kD * 4);
    bf16_t* wbf   = (bf16_t*)alloc((size_t)5 * kD * kD * 2);

    bf16_t* Winb = wbf;
    bf16_t* Walb = wbf + 1 * (size_t)kD * kD;
    bf16_t* Wbeb = wbf + 2 * (size_t)kD * kD;
    bf16_t* Wvb  = wbf + 3 * (size_t)kD * kD;
    bf16_t* Wob  = wbf + 4 * (size_t)kD * kD;

    bf16_t* cell = xbf;
    float*  Aagg = (float*)xp;
    float*  Bagg = Aagg + (size_t)kNC * kCH;
    float*  Hin  = Bagg + (size_t)kNC * kCH;

    // allow 128KB dynamic LDS (host-side, idempotent, not a stream op)
    hipFuncSetAttribute(reinterpret_cast<const void*>(gemm256<0>), hipFuncAttributeMaxDynamicSharedMemorySize, LDS_BYTES);
    hipFuncSetAttribute(reinterpret_cast<const void*>(gemm256<1>), hipFuncAttributeMaxDynamicSharedMemorySize, LDS_BYTES);
    hipFuncSetAttribute(reinterpret_cast<const void*>(gemm256<2>), hipFuncAttributeMaxDynamicSharedMemorySize, LDS_BYTES);
    hipFuncSetAttribute(reinterpret_cast<const void*>(gemm256<3>), hipFuncAttributeMaxDynamicSharedMemorySize, LDS_BYTES);

    // 1) casts to bf16
    {
        int n8 = kM * kD / 8;
        cvt_bf16_kernel<<<(n8 + 255) / 256, 256, 0, stream>>>(x, xbf, n8);
        int w8 = kD * kD / 8;
        int wg = (w8 + 255) / 256;
        cvt_bf16_kernel<<<wg, 256, 0, stream>>>(W_in,  Winb, w8);
        cvt_bf16_kernel<<<wg, 256, 0, stream>>>(W_al,  Walb, w8);
        cvt_bf16_kernel<<<wg, 256, 0, stream>>>(W_be,  Wbeb, w8);
        cvt_bf16_kernel<<<wg, 256, 0, stream>>>(W_v,   Wvb,  w8);
        cvt_bf16_kernel<<<wg, 256, 0, stream>>>(W_out, Wob,  w8);
    }

    dim3 grid(kD / 256, kM / 256);   // (4, 64) = 256 wgs

    // 2) xp = silu(x @ W_in^T)              [bf16]
    gemm256<0><<<grid, 512, LDS_BYTES, stream>>>(xbf, Winb, nullptr, nullptr, xp, kM, kD, kD);
    // 3) alpha = sigmoid(xp @ W_a^T + b_a)  [f32]
    gemm256<1><<<grid, 512, LDS_BYTES, stream>>>(xp, Walb, b_al, nullptr, alpha, kM, kD, kD);
    //    beta  = sigmoid(xp @ W_b^T + b_b)  [f32]
    gemm256<1><<<grid, 512, LDS_BYTES, stream>>>(xp, Wbeb, b_be, nullptr, bvb, kM, kD, kD);
    //    bv    = beta * tanh(xp @ W_v^T + b_v)  [f32, in place]
    gemm256<2><<<grid, 512, LDS_BYTES, stream>>>(xp, Wvb, b_v, bvb, bvb, kM, kD, kD);

    // 4) chunked scan
    scan_chunk_kernel<<<kNC * kCH / 256, 256, 0, stream>>>(alpha, bvb, Aagg, Bagg);
    scan_mid_kernel<<<kCH / 256, 256, 0, stream>>>(Aagg, Bagg, Hin, hlast);
    scan_out_kernel<<<kNC * kCH / 256, 256, 0, stream>>>(alpha, bvb, Hin, cell);

    // 5) output = cell @ W_out^T            [f32 -> d_out]
    gemm256<3><<<grid, 512, LDS_BYTES, stream>>>(cell, Wob, nullptr, nullptr, out, kM, kD, kD);
}

// Round 3
// 347.205 us; speedup vs baseline: 1.1613x; 1.0065x over previous
//
#include <hip/hip_runtime.h>
#include <hip/hip_bf16.h>
#include <cstdint>
#include <cstddef>

typedef __bf16 bf16_t;
typedef __bf16 bf16x8 __attribute__((ext_vector_type(8)));
typedef float  f32x4  __attribute__((ext_vector_type(4)));

constexpr int kBatch = 4;
constexpr int kT = 4096;
constexpr int kD = 1024;
constexpr int kM = kBatch * kT;     // 16384 rows
constexpr int kCH = kBatch * kD;    // 4096 scan channels
constexpr int kNC = 128;            // scan chunks
constexpr int kL  = kT / kNC;       // 32 steps per chunk
constexpr int LDS_BYTES = 131072;   // 2 bufs x (A 32K + B 32K)

// ---------------------------------------------------------------- helpers
__device__ __forceinline__ void async16(const bf16_t* g, char* l) {
    __builtin_amdgcn_global_load_lds(
        (const __attribute__((address_space(1))) uint32_t*)g,
        (__attribute__((address_space(3))) uint32_t*)l,
        16, 0, 0);
}

// ---------------------------------------------------------------- f32 -> bf16 cast (x)
__global__ void cvt_bf16_kernel(const float* __restrict__ in, bf16_t* __restrict__ out, int n8) {
    int i = blockIdx.x * blockDim.x + threadIdx.x;
    if (i >= n8) return;
    const float4* p = reinterpret_cast<const float4*>(in) + 2 * (size_t)i;
    float4 a = p[0], b = p[1];
    bf16x8 o;
    o[0] = (bf16_t)a.x; o[1] = (bf16_t)a.y; o[2] = (bf16_t)a.z; o[3] = (bf16_t)a.w;
    o[4] = (bf16_t)b.x; o[5] = (bf16_t)b.y; o[6] = (bf16_t)b.z; o[7] = (bf16_t)b.w;
    *reinterpret_cast<bf16x8*>(out + 8 * (size_t)i) = o;
}

// merged cast of the 5 weight matrices (each kD*kD) into contiguous wbf
__global__ void cvtw_kernel(const float* __restrict__ w0, const float* __restrict__ w1,
                            const float* __restrict__ w2, const float* __restrict__ w3,
                            const float* __restrict__ w4, bf16_t* __restrict__ out) {
    const int per = kD * kD / 8;   // chunks per weight
    int i = blockIdx.x * blockDim.x + threadIdx.x;
    int seg = i / per, j = i - seg * per;
    const float* src = seg == 0 ? w0 : seg == 1 ? w1 : seg == 2 ? w2 : seg == 3 ? w3 : w4;
    const float4* p = reinterpret_cast<const float4*>(src) + 2 * (size_t)j;
    float4 a = p[0], b = p[1];
    bf16x8 o;
    o[0] = (bf16_t)a.x; o[1] = (bf16_t)a.y; o[2] = (bf16_t)a.z; o[3] = (bf16_t)a.w;
    o[4] = (bf16_t)b.x; o[5] = (bf16_t)b.y; o[6] = (bf16_t)b.z; o[7] = (bf16_t)b.w;
    *reinterpret_cast<bf16x8*>(out + ((size_t)seg * per + j) * 8) = o;
}

// ---------------------------------------------------------------- 256x256 8-phase GEMM
// C[m][n] = sum_k A[m][k]*Bw[n][k].  BM=BN=256, BK=64, 8 waves (2M x 4N).
// EPI: 0 = silu -> bf16 (out0)
//      3 = plain f32 nt (out0)
//      4 = fused 3-slab: slab0 sigmoid(+bi0)->f32 out0 | slab1 sigmoid(+bi1)->bf16 out1
//          | slab2 tanh(+bi2)->bf16 out2   (slab = n0>>10, per-slab column = colg&1023)
template<int EPI>
__global__ __launch_bounds__(512, 2)
void gemm256(const bf16_t* __restrict__ A, const bf16_t* __restrict__ Bw,
             const float* __restrict__ bi0, const float* __restrict__ bi1,
             const float* __restrict__ bi2,
             void* __restrict__ out0, void* __restrict__ out1, void* __restrict__ out2,
             int M, int N, int K)
{
    extern __shared__ char lds[];
    const int tid  = threadIdx.x;
    const int lane = tid & 63;
    const int wv   = tid >> 6;
    const int wr   = wv >> 2;      // 0..1  (M waves)
    const int wc   = wv & 3;       // 0..3  (N waves)
    const int l16  = lane & 15;
    const int lhi  = lane >> 4;

    // ---- bijective XCD-chunk swizzle (nwg % 8 == 0 for all our grids) ----
    int bid = blockIdx.y * gridDim.x + blockIdx.x;
    int nwg = gridDim.x * gridDim.y;
    int swz = (bid & 7) * (nwg >> 3) + (bid >> 3);
    int gx  = N >> 8;
    int n0  = (swz % gx) << 8;
    int m0  = (swz / gx) << 8;

    // ---- staging per-thread constants (inverse-swizzled global offsets) ----
    auto goff = [&](int chunk) -> size_t {
        int st = chunk >> 6;               // 1KB subtile
        int ri = (chunk >> 2) & 15;        // inner row
        int cp = (chunk & 3) << 3;         // physical inner col (bf16)
        int cl = cp ^ (((ri >> 3) & 1) << 4);  // logical col (involution)
        int gr = ((st >> 1) << 4) + ri;    // row within 128-row half
        int gc = ((st & 1) << 5) + cl;     // col within BK=64
        return (size_t)gr * K + gc;
    };
    const size_t g0 = goff(tid), g1 = goff(512 + tid);
    const int d0 = wv << 10, d1 = 8192 + (wv << 10);   // linear LDS dest (wave base)

    auto STAGE = [&](const bf16_t* G, int row0, int k0, int lds_base) {
        const bf16_t* base = G + (size_t)row0 * K + k0;
        async16(base + g0, lds + lds_base + d0);
        async16(base + g1, lds + lds_base + d1);
    };

    // ---- swizzled ds_read offsets (relative to a half-region base) ----
    auto ldsoff = [&](int r, int c) -> int {
        int ri = r & 15;
        int st = ((r >> 4) << 1) | (c >> 5);
        int cw = (c & 31) ^ (((ri >> 3) & 1) << 4);
        return (st << 10) + (ri << 6) + (cw << 1);
    };
    int offA[4][2], offB[2][2];
#pragma unroll
    for (int m = 0; m < 4; ++m)
#pragma unroll
        for (int s = 0; s < 2; ++s)
            offA[m][s] = ldsoff(wr * 64 + m * 16 + l16, s * 32 + lhi * 8);
#pragma unroll
    for (int n = 0; n < 2; ++n)
#pragma unroll
        for (int s = 0; s < 2; ++s)
            offB[n][s] = ldsoff(wc * 32 + n * 16 + l16, s * 32 + lhi * 8);

    f32x4 acc[8][4];
#pragma unroll
    for (int i = 0; i < 8; ++i)
#pragma unroll
        for (int j = 0; j < 4; ++j)
            acc[i][j] = (f32x4){0.f, 0.f, 0.f, 0.f};

    const int NT = K >> 6;   // 16

    // ---- prologue: tile0 all 4 halves, then tile1 {Alo, Bhi, Ahi} ----
    STAGE(A,  m0,        0, 0);
    STAGE(A,  m0 + 128,  0, 16384);
    STAGE(Bw, n0,        0, 32768);
    STAGE(Bw, n0 + 128,  0, 49152);
    STAGE(A,  m0,       64, 65536);
    STAGE(Bw, n0 + 128, 64, 65536 + 49152);
    STAGE(A,  m0 + 128, 64, 65536 + 16384);
    asm volatile("s_waitcnt vmcnt(6)" ::: "memory");
    asm volatile("s_barrier" ::: "memory");

    for (int w = 0; w < NT; ++w) {
        const int bufo  = (w & 1) << 16;
        const int nbufo = bufo ^ 65536;
        const int oA0 = bufo, oA1 = bufo + 16384;
        const int oB0 = bufo + 32768, oB1 = bufo + 49152;
        const int k1 = (w + 1) << 6, k2 = (w + 2) << 6;
        bf16x8 aL[4][2], aH[4][2], bL[2][2], bH[2][2];

        // ===== P1: read Alo,Blo ; stage Blo(w+1) ; Q0 =====
#pragma unroll
        for (int m = 0; m < 4; ++m)
#pragma unroll
            for (int s = 0; s < 2; ++s)
                aL[m][s] = *reinterpret_cast<const bf16x8*>(lds + oA0 + offA[m][s]);
#pragma unroll
        for (int n = 0; n < 2; ++n)
#pragma unroll
            for (int s = 0; s < 2; ++s)
                bL[n][s] = *reinterpret_cast<const bf16x8*>(lds + oB0 + offB[n][s]);
        if (w + 1 < NT) STAGE(Bw, n0, k1, nbufo + 32768);
        asm volatile("s_barrier" ::: "memory");
        __builtin_amdgcn_s_setprio(1);
#pragma unroll
        for (int m = 0; m < 4; ++m)
#pragma unroll
            for (int n = 0; n < 2; ++n)
#pragma unroll
                for (int s = 0; s < 2; ++s)
                    acc[m][n] = __builtin_amdgcn_mfma_f32_16x16x32_bf16(aL[m][s], bL[n][s], acc[m][n], 0, 0, 0);
        __builtin_amdgcn_s_setprio(0);
        asm volatile("s_barrier" ::: "memory");

        // ===== P2: read Bhi ; stage Alo(w+2) ; Q1 =====
#pragma unroll
        for (int n = 0; n < 2; ++n)
#pragma unroll
            for (int s = 0; s < 2; ++s)
                bH[n][s] = *reinterpret_cast<const bf16x8*>(lds + oB1 + offB[n][s]);
        if (w + 2 < NT) STAGE(A, m0, k2, oA0);
        asm volatile("s_barrier" ::: "memory");
        __builtin_amdgcn_s_setprio(1);
#pragma unroll
        for (int m = 0; m < 4; ++m)
#pragma unroll
            for (int n = 0; n < 2; ++n)
#pragma unroll
                for (int s = 0; s < 2; ++s)
                    acc[m][2 + n] = __builtin_amdgcn_mfma_f32_16x16x32_bf16(aL[m][s], bH[n][s], acc[m][2 + n], 0, 0, 0);
        __builtin_amdgcn_s_setprio(0);
        asm volatile("s_barrier" ::: "memory");

        // ===== P3: read Ahi ; stage Bhi(w+2) ; Q2 =====
#pragma unroll
        for (int m = 0; m < 4; ++m)
#pragma unroll
            for (int s = 0; s < 2; ++s)
                aH[m][s] = *reinterpret_cast<const bf16x8*>(lds + oA1 + offA[m][s]);
        if (w + 2 < NT) STAGE(Bw, n0 + 128, k2, oB1);
        asm volatile("s_barrier" ::: "memory");
        __builtin_amdgcn_s_setprio(1);
#pragma unroll
        for (int m = 0; m < 4; ++m)
#pragma unroll
            for (int n = 0; n < 2; ++n)
#pragma unroll
                for (int s = 0; s < 2; ++s)
                    acc[4 + m][n] = __builtin_amdgcn_mfma_f32_16x16x32_bf16(aH[m][s], bL[n][s], acc[4 + m][n], 0, 0, 0);
        __builtin_amdgcn_s_setprio(0);
        asm volatile("s_barrier" ::: "memory");

        // ===== P4: stage Ahi(w+2) ; Q3 ; counted vmcnt ; barrier =====
        if (w + 2 < NT) STAGE(A, m0 + 128, k2, oA1);
        asm volatile("s_barrier" ::: "memory");
        __builtin_amdgcn_s_setprio(1);
#pragma unroll
        for (int m = 0; m < 4; ++m)
#pragma unroll
            for (int n = 0; n < 2; ++n)
#pragma unroll
                for (int s = 0; s < 2; ++s)
                    acc[4 + m][2 + n] = __builtin_amdgcn_mfma_f32_16x16x32_bf16(aH[m][s], bH[n][s], acc[4 + m][2 + n], 0, 0, 0);
        __builtin_amdgcn_s_setprio(0);
        if (w + 2 < NT) {
            asm volatile("s_waitcnt vmcnt(6)" ::: "memory");
        } else if (w + 2 == NT) {
            asm volatile("s_waitcnt vmcnt(0)" ::: "memory");
        }
        if (w + 1 < NT) asm volatile("s_barrier" ::: "memory");
    }

    // ---- epilogue: C/D layout col=lane&15, row=(lane>>4)*4+r ----
    const int slab = n0 >> 10;                 // wave-uniform (EPI==4)
    const float* bia = (EPI == 4) ? (slab == 0 ? bi0 : slab == 1 ? bi1 : bi2) : nullptr;
#pragma unroll
    for (int j = 0; j < 4; ++j) {
        const int colg = n0 + ((j >> 1) << 7) + wc * 32 + (j & 1) * 16 + l16;
        const int cL = colg & (kD - 1);
        float bs = 0.f;
        if constexpr (EPI == 4) bs = bia[cL];
#pragma unroll
        for (int i = 0; i < 8; ++i) {
            const int rb = m0 + ((i >> 2) << 7) + wr * 64 + (i & 3) * 16 + lhi * 4;
#pragma unroll
            for (int r = 0; r < 4; ++r) {
                const int rowg = rb + r;
                const float f = acc[i][j][r];
                if constexpr (EPI == 0) {
                    float s = f / (1.f + __expf(-f));
                    reinterpret_cast<bf16_t*>(out0)[(size_t)rowg * N + colg] = (bf16_t)s;
                } else if constexpr (EPI == 3) {
                    __builtin_nontemporal_store(f, reinterpret_cast<float*>(out0) + (size_t)rowg * N + colg);
                } else {  // EPI == 4
                    const size_t idx = (size_t)rowg * kD + cL;
                    if (slab == 0) {
                        float s = 1.f / (1.f + __expf(-(f + bs)));
                        __builtin_nontemporal_store(s, reinterpret_cast<float*>(out0) + idx);
                    } else if (slab == 1) {
                        float s = 1.f / (1.f + __expf(-(f + bs)));
                        __builtin_nontemporal_store((bf16_t)s, reinterpret_cast<bf16_t*>(out1) + idx);
                    } else {
                        float s = tanhf(f + bs);
                        __builtin_nontemporal_store((bf16_t)s, reinterpret_cast<bf16_t*>(out2) + idx);
                    }
                }
            }
        }
    }
}

// ---------------------------------------------------------------- chunked linear scan
// h_t = a_t*h + beta_t*v_t ; alpha f32, beta/v bf16.
__global__ void scan_chunk_kernel(const float* __restrict__ alpha,
                                  const bf16_t* __restrict__ beta,
                                  const bf16_t* __restrict__ vv,
                                  float* __restrict__ Aagg,
                                  float* __restrict__ Bagg)
{
    const int u  = blockIdx.x * blockDim.x + threadIdx.x;
    const int ch = u & (kCH - 1);
    const int c  = u >> 12;
    const int b  = ch >> 10;
    const int d  = ch & (kD - 1);
    size_t base = ((size_t)b * kT + (size_t)c * kL) * kD + d;
    float Ac = 1.f, Bc = 0.f;
#pragma unroll 4
    for (int t = 0; t < kL; ++t) {
        float a  = alpha[base];
        float bv = (float)beta[base] * (float)vv[base];
        Ac *= a;
        Bc = a * Bc + bv;
        base += kD;
    }
    Aagg[u] = Ac;
    Bagg[u] = Bc;
}

__global__ void scan_mid_kernel(const float* __restrict__ Aagg,
                                const float* __restrict__ Bagg,
                                float* __restrict__ Hin,
                                float* __restrict__ hlast)
{
    const int ch = blockIdx.x * blockDim.x + threadIdx.x;
    float h = 0.f;
#pragma unroll 8
    for (int c = 0; c < kNC; ++c) {
        Hin[(size_t)c * kCH + ch] = h;
        h = Aagg[(size_t)c * kCH + ch] * h + Bagg[(size_t)c * kCH + ch];
    }
    hlast[ch] = h;
}

__global__ void scan_out_kernel(const float* __restrict__ alpha,
                                const bf16_t* __restrict__ beta,
                                const bf16_t* __restrict__ vv,
                                const float* __restrict__ Hin,
                                bf16_t* __restrict__ cell)
{
    const int u  = blockIdx.x * blockDim.x + threadIdx.x;
    const int ch = u & (kCH - 1);
    const int c  = u >> 12;
    const int b  = ch >> 10;
    const int d  = ch & (kD - 1);
    size_t base = ((size_t)b * kT + (size_t)c * kL) * kD + d;
    float h = Hin[u];
#pragma unroll 4
    for (int t = 0; t < kL; ++t) {
        float a  = alpha[base];
        float bv = (float)beta[base] * (float)vv[base];
        h = a * h + bv;
        float s = 1.f / (1.f + __expf(-h));
        cell[base] = (bf16_t)(h * h * s);
        base += kD;
    }
}

// ---------------------------------------------------------------- launch
extern "C" void kernel_launch(void* const* d_in, const int* in_sizes, int n_in,
                              void* d_out, int out_size, void* d_ws, size_t ws_size,
                              hipStream_t stream)
{
    const float* x     = (const float*)d_in[0];
    const float* W_in  = (const float*)d_in[1];
    const float* W_al  = (const float*)d_in[2];
    const float* b_al  = (const float*)d_in[3];
    const float* W_be  = (const float*)d_in[4];
    const float* b_be  = (const float*)d_in[5];
    const float* W_v   = (const float*)d_in[6];
    const float* b_v   = (const float*)d_in[7];
    const float* W_out = (const float*)d_in[8];

    float* out   = (float*)d_out;
    float* hlast = out + (size_t)kM * kD;

    char* ws = (char*)d_ws;
    size_t off = 0;
    auto alloc = [&](size_t bytes) -> void* {
        void* p = ws + off;
        off += (bytes + 255) & ~(size_t)255;
        return p;
    };
    bf16_t* xbf   = (bf16_t*)alloc((size_t)kM * kD * 2);   // dead after GEMM1 -> cell
    bf16_t* xp    = (bf16_t*)alloc((size_t)kM * kD * 2);   // dead after fused -> aggs
    float*  alpha = (float*) alloc((size_t)kM * kD * 4);
    bf16_t* betab = (bf16_t*)alloc((size_t)kM * kD * 2);
    bf16_t* vb    = (bf16_t*)alloc((size_t)kM * kD * 2);
    bf16_t* wbf   = (bf16_t*)alloc((size_t)5 * kD * kD * 2);

    bf16_t* Winb = wbf;                      // [W_in; W_al; W_be; W_v; W_out]
    bf16_t* Wfus = wbf + 1 * (size_t)kD * kD;   // fused B: rows 0..3071
    bf16_t* Wob  = wbf + 4 * (size_t)kD * kD;

    bf16_t* cell = xbf;
    float*  Aagg = (float*)xp;
    float*  Bagg = Aagg + (size_t)kNC * kCH;
    float*  Hin  = Bagg + (size_t)kNC * kCH;

    hipFuncSetAttribute(reinterpret_cast<const void*>(gemm256<0>), hipFuncAttributeMaxDynamicSharedMemorySize, LDS_BYTES);
    hipFuncSetAttribute(reinterpret_cast<const void*>(gemm256<3>), hipFuncAttributeMaxDynamicSharedMemorySize, LDS_BYTES);
    hipFuncSetAttribute(reinterpret_cast<const void*>(gemm256<4>), hipFuncAttributeMaxDynamicSharedMemorySize, LDS_BYTES);

    // 1) casts to bf16
    {
        int n8 = kM * kD / 8;
        cvt_bf16_kernel<<<(n8 + 255) / 256, 256, 0, stream>>>(x, xbf, n8);
        int wtot = 5 * kD * kD / 8;
        cvtw_kernel<<<(wtot + 255) / 256, 256, 0, stream>>>(W_in, W_al, W_be, W_v, W_out, wbf);
    }

    dim3 grid1(kD / 256, kM / 256);     // (4, 64)  = 256 wgs
    dim3 gridF(3 * kD / 256, kM / 256); // (12, 64) = 768 wgs

    // 2) xp = silu(x @ W_in^T)                       [bf16]
    gemm256<0><<<grid1, 512, LDS_BYTES, stream>>>(xbf, Winb, nullptr, nullptr, nullptr,
                                                  xp, nullptr, nullptr, kM, kD, kD);
    // 3) fused: alpha=sigmoid(+b_al) f32 | beta=sigmoid(+b_be) bf16 | v=tanh(+b_v) bf16
    gemm256<4><<<gridF, 512, LDS_BYTES, stream>>>(xp, Wfus, b_al, b_be, b_v,
                                                  alpha, betab, vb, kM, 3 * kD, kD);
    // 4) chunked scan (bv = beta*v on the fly)
    scan_chunk_kernel<<<kNC * kCH / 256, 256, 0, stream>>>(alpha, betab, vb, Aagg, Bagg);
    scan_mid_kernel<<<kCH / 256, 256, 0, stream>>>(Aagg, Bagg, Hin, hlast);
    scan_out_kernel<<<kNC * kCH / 256, 256, 0, stream>>>(alpha, betab, vb, Hin, cell);

    // 5) output = cell @ W_out^T                     [f32 nt -> d_out]
    gemm256<3><<<grid1, 512, LDS_BYTES, stream>>>(cell, Wob, nullptr, nullptr, nullptr,
                                                  out, nullptr, nullptr, kM, kD, kD);
}

// Round 4
// 346.637 us; speedup vs baseline: 1.1632x; 1.0016x over previous
//
#include <hip/hip_runtime.h>
#include <hip/hip_bf16.h>
#include <cstdint>
#include <cstddef>

typedef __bf16 bf16_t;
typedef _Float16 f16_t;
typedef __bf16 bf16x8 __attribute__((ext_vector_type(8)));
typedef float  f32x4  __attribute__((ext_vector_type(4)));

constexpr int kBatch = 4;
constexpr int kT = 4096;
constexpr int kD = 1024;
constexpr int kM = kBatch * kT;     // 16384 rows
constexpr int kCH = kBatch * kD;    // 4096 scan channels
constexpr int kNC = 128;            // scan chunks
constexpr int kL  = kT / kNC;       // 32 steps per chunk
constexpr int LDS_BYTES = 49152;    // 2 bufs x (A 8K + B0 8K + B1 8K)

// ---------------------------------------------------------------- helpers
__device__ __forceinline__ void async16(const bf16_t* g, char* l) {
    __builtin_amdgcn_global_load_lds(
        (const __attribute__((address_space(1))) uint32_t*)g,
        (__attribute__((address_space(3))) uint32_t*)l,
        16, 0, 0);
}

// ---------------------------------------------------------------- f32 -> bf16 cast (x)
__global__ void cvt_bf16_kernel(const float* __restrict__ in, bf16_t* __restrict__ out, int n8) {
    int i = blockIdx.x * blockDim.x + threadIdx.x;
    if (i >= n8) return;
    const float4* p = reinterpret_cast<const float4*>(in) + 2 * (size_t)i;
    float4 a = p[0], b = p[1];
    bf16x8 o;
    o[0] = (bf16_t)a.x; o[1] = (bf16_t)a.y; o[2] = (bf16_t)a.z; o[3] = (bf16_t)a.w;
    o[4] = (bf16_t)b.x; o[5] = (bf16_t)b.y; o[6] = (bf16_t)b.z; o[7] = (bf16_t)b.w;
    *reinterpret_cast<bf16x8*>(out + 8 * (size_t)i) = o;
}

// merged cast of the 5 weight matrices (each kD*kD) into contiguous wbf
__global__ void cvtw_kernel(const float* __restrict__ w0, const float* __restrict__ w1,
                            const float* __restrict__ w2, const float* __restrict__ w3,
                            const float* __restrict__ w4, bf16_t* __restrict__ out) {
    const int per = kD * kD / 8;
    int i = blockIdx.x * blockDim.x + threadIdx.x;
    int seg = i / per, j = i - seg * per;
    const float* src = seg == 0 ? w0 : seg == 1 ? w1 : seg == 2 ? w2 : seg == 3 ? w3 : w4;
    const float4* p = reinterpret_cast<const float4*>(src) + 2 * (size_t)j;
    float4 a = p[0], b = p[1];
    bf16x8 o;
    o[0] = (bf16_t)a.x; o[1] = (bf16_t)a.y; o[2] = (bf16_t)a.z; o[3] = (bf16_t)a.w;
    o[4] = (bf16_t)b.x; o[5] = (bf16_t)b.y; o[6] = (bf16_t)b.z; o[7] = (bf16_t)b.w;
    *reinterpret_cast<bf16x8*>(out + ((size_t)seg * per + j) * 8) = o;
}

// ---------------------------------------------------------------- 128x256 BK=32 GEMM, 2 blocks/CU
// C[m][n] = sum_k A[m][k]*Bw[n][k].  BM=128, BN=256, BK=32, 8 waves (2M x 4N),
// per-wave 64x64 out. LDS: 2 bufs x {A[128][32], B0[128][32], B1[128][32]} bf16
// (48 KB) -> 2 workgroups/CU. st_16x32 XOR swizzle via pre-swizzled global src.
// Per K-tile 4 phases (quadrants m01/m23 x n01/n23), stages: P2:B0(w+2)
// P3:B1(w+2) P4:A(w+2) each into regions fully read >=1 barrier earlier.
// vmcnt(3) at P4 (1 load/thread/chunk; 3 newest stay in flight).
// EPI: 0 silu->bf16 | 3 f32 nt | 4 slab0 sigmoid->f16 / slab1 sigmoid->bf16 /
//      slab2 tanh->bf16
template<int EPI>
__global__ __launch_bounds__(512, 4)
void gemm128(const bf16_t* __restrict__ A, const bf16_t* __restrict__ Bw,
             const float* __restrict__ bi0, const float* __restrict__ bi1,
             const float* __restrict__ bi2,
             void* __restrict__ out0, void* __restrict__ out1, void* __restrict__ out2,
             int M, int N, int K)
{
    extern __shared__ char lds[];
    const int tid  = threadIdx.x;
    const int lane = tid & 63;
    const int wv   = tid >> 6;
    const int wr   = wv >> 2;      // 0..1  (M waves, 64 rows each)
    const int wc   = wv & 3;       // 0..3  (N waves, 64 cols each incl. 128-split)
    const int l16  = lane & 15;
    const int lhi  = lane >> 4;

    // ---- bijective XCD-chunk swizzle (nwg % 8 == 0 for all our grids) ----
    int bid = blockIdx.y * gridDim.x + blockIdx.x;
    int nwg = gridDim.x * gridDim.y;
    int swz = (bid & 7) * (nwg >> 3) + (bid >> 3);
    int gx  = N >> 8;
    int n0  = (swz % gx) << 8;
    int m0  = (swz / gx) << 7;     // BM=128

    // ---- staging map: LDS byte = tid*16 (linear); source pre-swizzled ----
    const int sri = (tid >> 2) & 15;              // inner row of 16x32 subtile
    const int scl = ((tid & 3) << 3) ^ ((sri & 8) << 1);  // logical col (involution)
    const int grow = ((tid >> 6) << 4) + sri;     // global row 0..127

    auto STAGE = [&](const bf16_t* G, int row0, int k0, int region) {
        async16(G + (size_t)(row0 + grow) * K + k0 + scl, lds + region + tid * 16);
    };

    // ---- swizzled ds_read offsets within a 128x32 region ----
    auto off = [&](int r, int c) -> int {
        return ((r >> 4) << 10) + ((r & 15) << 6) + ((c ^ ((r & 8) << 1)) << 1);
    };
    int offA[4], offB[4];
#pragma unroll
    for (int m = 0; m < 4; ++m)
        offA[m] = off(wr * 64 + m * 16 + l16, lhi * 8);
#pragma unroll
    for (int n = 0; n < 4; ++n)
        offB[n] = 8192 + (n >> 1) * 8192 + off(wc * 32 + (n & 1) * 16 + l16, lhi * 8);

    f32x4 acc[4][4];
#pragma unroll
    for (int i = 0; i < 4; ++i)
#pragma unroll
        for (int j = 0; j < 4; ++j)
            acc[i][j] = (f32x4){0.f, 0.f, 0.f, 0.f};

    const int NT = K >> 5;   // 32

    // ---- prologue: tile0 {A,B0,B1} -> buf0, tile1 -> buf1 ----
    STAGE(A,  m0,       0, 0);
    STAGE(Bw, n0,       0, 8192);
    STAGE(Bw, n0 + 128, 0, 16384);
    STAGE(A,  m0,       32, 24576);
    STAGE(Bw, n0,       32, 24576 + 8192);
    STAGE(Bw, n0 + 128, 32, 24576 + 16384);
    asm volatile("s_waitcnt vmcnt(3)" ::: "memory");
    asm volatile("s_barrier" ::: "memory");

    for (int w = 0; w < NT; ++w) {
        const int bufo = (w & 1) * 24576;
        const int k2   = (w + 2) << 5;
        bf16x8 aLo[2], aHi[2], bLo[2], bHi[2];

        // ===== P1: read aLo,bLo ; Q0 (m01 x n01) =====
        aLo[0] = *reinterpret_cast<const bf16x8*>(lds + bufo + offA[0]);
        aLo[1] = *reinterpret_cast<const bf16x8*>(lds + bufo + offA[1]);
        bLo[0] = *reinterpret_cast<const bf16x8*>(lds + bufo + offB[0]);
        bLo[1] = *reinterpret_cast<const bf16x8*>(lds + bufo + offB[1]);
        asm volatile("s_barrier" ::: "memory");
        __builtin_amdgcn_s_setprio(1);
        acc[0][0] = __builtin_amdgcn_mfma_f32_16x16x32_bf16(aLo[0], bLo[0], acc[0][0], 0, 0, 0);
        acc[0][1] = __builtin_amdgcn_mfma_f32_16x16x32_bf16(aLo[0], bLo[1], acc[0][1], 0, 0, 0);
        acc[1][0] = __builtin_amdgcn_mfma_f32_16x16x32_bf16(aLo[1], bLo[0], acc[1][0], 0, 0, 0);
        acc[1][1] = __builtin_amdgcn_mfma_f32_16x16x32_bf16(aLo[1], bLo[1], acc[1][1], 0, 0, 0);
        __builtin_amdgcn_s_setprio(0);
        asm volatile("s_barrier" ::: "memory");

        // ===== P2: read bHi ; stage B0(w+2) ; Q1 (m01 x n23) =====
        bHi[0] = *reinterpret_cast<const bf16x8*>(lds + bufo + offB[2]);
        bHi[1] = *reinterpret_cast<const bf16x8*>(lds + bufo + offB[3]);
        if (w + 2 < NT) STAGE(Bw, n0, k2, bufo + 8192);
        asm volatile("s_barrier" ::: "memory");
        __builtin_amdgcn_s_setprio(1);
        acc[0][2] = __builtin_amdgcn_mfma_f32_16x16x32_bf16(aLo[0], bHi[0], acc[0][2], 0, 0, 0);
        acc[0][3] = __builtin_amdgcn_mfma_f32_16x16x32_bf16(aLo[0], bHi[1], acc[0][3], 0, 0, 0);
        acc[1][2] = __builtin_amdgcn_mfma_f32_16x16x32_bf16(aLo[1], bHi[0], acc[1][2], 0, 0, 0);
        acc[1][3] = __builtin_amdgcn_mfma_f32_16x16x32_bf16(aLo[1], bHi[1], acc[1][3], 0, 0, 0);
        __builtin_amdgcn_s_setprio(0);
        asm volatile("s_barrier" ::: "memory");

        // ===== P3: read aHi ; stage B1(w+2) ; Q2 (m23 x n01) =====
        aHi[0] = *reinterpret_cast<const bf16x8*>(lds + bufo + offA[2]);
        aHi[1] = *reinterpret_cast<const bf16x8*>(lds + bufo + offA[3]);
        if (w + 2 < NT) STAGE(Bw, n0 + 128, k2, bufo + 16384);
        asm volatile("s_barrier" ::: "memory");
        __builtin_amdgcn_s_setprio(1);
        acc[2][0] = __builtin_amdgcn_mfma_f32_16x16x32_bf16(aHi[0], bLo[0], acc[2][0], 0, 0, 0);
        acc[2][1] = __builtin_amdgcn_mfma_f32_16x16x32_bf16(aHi[0], bLo[1], acc[2][1], 0, 0, 0);
        acc[3][0] = __builtin_amdgcn_mfma_f32_16x16x32_bf16(aHi[1], bLo[0], acc[3][0], 0, 0, 0);
        acc[3][1] = __builtin_amdgcn_mfma_f32_16x16x32_bf16(aHi[1], bLo[1], acc[3][1], 0, 0, 0);
        __builtin_amdgcn_s_setprio(0);
        asm volatile("s_barrier" ::: "memory");

        // ===== P4: stage A(w+2) ; Q3 (m23 x n23) ; counted vmcnt ; barrier =====
        if (w + 2 < NT) STAGE(A, m0, k2, bufo);
        asm volatile("s_barrier" ::: "memory");
        __builtin_amdgcn_s_setprio(1);
        acc[2][2] = __builtin_amdgcn_mfma_f32_16x16x32_bf16(aHi[0], bHi[0], acc[2][2], 0, 0, 0);
        acc[2][3] = __builtin_amdgcn_mfma_f32_16x16x32_bf16(aHi[0], bHi[1], acc[2][3], 0, 0, 0);
        acc[3][2] = __builtin_amdgcn_mfma_f32_16x16x32_bf16(aHi[1], bHi[0], acc[3][2], 0, 0, 0);
        acc[3][3] = __builtin_amdgcn_mfma_f32_16x16x32_bf16(aHi[1], bHi[1], acc[3][3], 0, 0, 0);
        __builtin_amdgcn_s_setprio(0);
        if (w + 2 < NT) {
            asm volatile("s_waitcnt vmcnt(3)" ::: "memory");
        } else if (w + 1 < NT) {
            asm volatile("s_waitcnt vmcnt(0)" ::: "memory");
        }
        if (w + 1 < NT) asm volatile("s_barrier" ::: "memory");
    }

    // ---- epilogue: C/D layout col=lane&15, row=(lane>>4)*4+r ----
    const int slab = n0 >> 10;                 // block-uniform (EPI==4)
    const float* bia = (EPI == 4) ? (slab == 0 ? bi0 : slab == 1 ? bi1 : bi2) : nullptr;
#pragma unroll
    for (int j = 0; j < 4; ++j) {
        const int colg = n0 + ((j >> 1) << 7) + wc * 32 + (j & 1) * 16 + l16;
        const int cL = colg & (kD - 1);
        float bs = 0.f;
        if constexpr (EPI == 4) bs = bia[cL];
#pragma unroll
        for (int i = 0; i < 4; ++i) {
            const int rb = m0 + wr * 64 + i * 16 + lhi * 4;
#pragma unroll
            for (int r = 0; r < 4; ++r) {
                const int rowg = rb + r;
                const float f = acc[i][j][r];
                if constexpr (EPI == 0) {
                    float s = f / (1.f + __expf(-f));
                    reinterpret_cast<bf16_t*>(out0)[(size_t)rowg * N + colg] = (bf16_t)s;
                } else if constexpr (EPI == 3) {
                    __builtin_nontemporal_store(f, reinterpret_cast<float*>(out0) + (size_t)rowg * N + colg);
                } else {  // EPI == 4
                    const size_t idx = (size_t)rowg * kD + cL;
                    if (slab == 0) {
                        float s = 1.f / (1.f + __expf(-(f + bs)));
                        __builtin_nontemporal_store((f16_t)s, reinterpret_cast<f16_t*>(out0) + idx);
                    } else if (slab == 1) {
                        float s = 1.f / (1.f + __expf(-(f + bs)));
                        __builtin_nontemporal_store((bf16_t)s, reinterpret_cast<bf16_t*>(out1) + idx);
                    } else {
                        float s = tanhf(f + bs);
                        __builtin_nontemporal_store((bf16_t)s, reinterpret_cast<bf16_t*>(out2) + idx);
                    }
                }
            }
        }
    }
}

// ---------------------------------------------------------------- chunked linear scan
// h_t = a_t*h + beta_t*v_t ; alpha fp16, beta/v bf16.
__global__ void scan_chunk_kernel(const f16_t* __restrict__ alpha,
                                  const bf16_t* __restrict__ beta,
                                  const bf16_t* __restrict__ vv,
                                  float* __restrict__ Aagg,
                                  float* __restrict__ Bagg)
{
    const int u  = blockIdx.x * blockDim.x + threadIdx.x;
    const int ch = u & (kCH - 1);
    const int c  = u >> 12;
    const int b  = ch >> 10;
    const int d  = ch & (kD - 1);
    size_t base = ((size_t)b * kT + (size_t)c * kL) * kD + d;
    float Ac = 1.f, Bc = 0.f;
#pragma unroll 4
    for (int t = 0; t < kL; ++t) {
        float a  = (float)alpha[base];
        float bv = (float)beta[base] * (float)vv[base];
        Ac *= a;
        Bc = a * Bc + bv;
        base += kD;
    }
    Aagg[u] = Ac;
    Bagg[u] = Bc;
}

__global__ void scan_mid_kernel(const float* __restrict__ Aagg,
                                const float* __restrict__ Bagg,
                                float* __restrict__ Hin,
                                float* __restrict__ hlast)
{
    const int ch = blockIdx.x * blockDim.x + threadIdx.x;
    float h = 0.f;
#pragma unroll 8
    for (int c = 0; c < kNC; ++c) {
        Hin[(size_t)c * kCH + ch] = h;
        h = Aagg[(size_t)c * kCH + ch] * h + Bagg[(size_t)c * kCH + ch];
    }
    hlast[ch] = h;
}

__global__ void scan_out_kernel(const f16_t* __restrict__ alpha,
                                const bf16_t* __restrict__ beta,
                                const bf16_t* __restrict__ vv,
                                const float* __restrict__ Hin,
                                bf16_t* __restrict__ cell)
{
    const int u  = blockIdx.x * blockDim.x + threadIdx.x;
    const int ch = u & (kCH - 1);
    const int c  = u >> 12;
    const int b  = ch >> 10;
    const int d  = ch & (kD - 1);
    size_t base = ((size_t)b * kT + (size_t)c * kL) * kD + d;
    float h = Hin[u];
#pragma unroll 4
    for (int t = 0; t < kL; ++t) {
        float a  = (float)alpha[base];
        float bv = (float)beta[base] * (float)vv[base];
        h = a * h + bv;
        float s = 1.f / (1.f + __expf(-h));
        cell[base] = (bf16_t)(h * h * s);
        base += kD;
    }
}

// ---------------------------------------------------------------- launch
extern "C" void kernel_launch(void* const* d_in, const int* in_sizes, int n_in,
                              void* d_out, int out_size, void* d_ws, size_t ws_size,
                              hipStream_t stream)
{
    const float* x     = (const float*)d_in[0];
    const float* W_in  = (const float*)d_in[1];
    const float* W_al  = (const float*)d_in[2];
    const float* b_al  = (const float*)d_in[3];
    const float* W_be  = (const float*)d_in[4];
    const float* b_be  = (const float*)d_in[5];
    const float* W_v   = (const float*)d_in[6];
    const float* b_v   = (const float*)d_in[7];
    const float* W_out = (const float*)d_in[8];

    float* out   = (float*)d_out;
    float* hlast = out + (size_t)kM * kD;

    char* ws = (char*)d_ws;
    size_t off = 0;
    auto alloc = [&](size_t bytes) -> void* {
        void* p = ws + off;
        off += (bytes + 255) & ~(size_t)255;
        return p;
    };
    bf16_t* xbf   = (bf16_t*)alloc((size_t)kM * kD * 2);   // dead after GEMM1 -> cell
    bf16_t* xp    = (bf16_t*)alloc((size_t)kM * kD * 2);   // dead after fused -> aggs
    f16_t*  alpha = (f16_t*) alloc((size_t)kM * kD * 2);
    bf16_t* betab = (bf16_t*)alloc((size_t)kM * kD * 2);
    bf16_t* vb    = (bf16_t*)alloc((size_t)kM * kD * 2);
    bf16_t* wbf   = (bf16_t*)alloc((size_t)5 * kD * kD * 2);

    bf16_t* Winb = wbf;                         // [W_in; W_al; W_be; W_v; W_out]
    bf16_t* Wfus = wbf + 1 * (size_t)kD * kD;   // fused B: rows 0..3071
    bf16_t* Wob  = wbf + 4 * (size_t)kD * kD;

    bf16_t* cell = xbf;
    float*  Aagg = (float*)xp;
    float*  Bagg = Aagg + (size_t)kNC * kCH;
    float*  Hin  = Bagg + (size_t)kNC * kCH;

    hipFuncSetAttribute(reinterpret_cast<const void*>(gemm128<0>), hipFuncAttributeMaxDynamicSharedMemorySize, LDS_BYTES);
    hipFuncSetAttribute(reinterpret_cast<const void*>(gemm128<3>), hipFuncAttributeMaxDynamicSharedMemorySize, LDS_BYTES);
    hipFuncSetAttribute(reinterpret_cast<const void*>(gemm128<4>), hipFuncAttributeMaxDynamicSharedMemorySize, LDS_BYTES);

    // 1) casts to bf16
    {
        int n8 = kM * kD / 8;
        cvt_bf16_kernel<<<(n8 + 255) / 256, 256, 0, stream>>>(x, xbf, n8);
        int wtot = 5 * kD * kD / 8;
        cvtw_kernel<<<(wtot + 255) / 256, 256, 0, stream>>>(W_in, W_al, W_be, W_v, W_out, wbf);
    }

    dim3 grid1(kD / 256, kM / 128);     // (4, 128)  = 512 wgs = 2/CU
    dim3 gridF(3 * kD / 256, kM / 128); // (12, 128) = 1536 wgs

    // 2) xp = silu(x @ W_in^T)                       [bf16]
    gemm128<0><<<grid1, 512, LDS_BYTES, stream>>>(xbf, Winb, nullptr, nullptr, nullptr,
                                                  xp, nullptr, nullptr, kM, kD, kD);
    // 3) fused: alpha=sigmoid(+b_al) f16 | beta=sigmoid(+b_be) bf16 | v=tanh(+b_v) bf16
    gemm128<4><<<gridF, 512, LDS_BYTES, stream>>>(xp, Wfus, b_al, b_be, b_v,
                                                  alpha, betab, vb, kM, 3 * kD, kD);
    // 4) chunked scan (bv = beta*v on the fly)
    scan_chunk_kernel<<<kNC * kCH / 256, 256, 0, stream>>>(alpha, betab, vb, Aagg, Bagg);
    scan_mid_kernel<<<kCH / 256, 256, 0, stream>>>(Aagg, Bagg, Hin, hlast);
    scan_out_kernel<<<kNC * kCH / 256, 256, 0, stream>>>(alpha, betab, vb, Hin, cell);

    // 5) output = cell @ W_out^T                     [f32 nt -> d_out]
    gemm128<3><<<grid1, 512, LDS_BYTES, stream>>>(cell, Wob, nullptr, nullptr, nullptr,
                                                  out, nullptr, nullptr, kM, kD, kD);
}

// Round 5
// 342.125 us; speedup vs baseline: 1.1786x; 1.0132x over previous
//
#include <hip/hip_runtime.h>
#include <hip/hip_bf16.h>
#include <cstdint>
#include <cstddef>

typedef __bf16 bf16_t;
typedef _Float16 f16_t;
typedef __bf16 bf16x8 __attribute__((ext_vector_type(8)));
typedef float  f32x4  __attribute__((ext_vector_type(4)));

constexpr int kBatch = 4;
constexpr int kT = 4096;
constexpr int kD = 1024;
constexpr int kM = kBatch * kT;     // 16384 rows
constexpr int kCH = kBatch * kD;    // 4096 scan channels
constexpr int kNC = 128;            // scan chunks
constexpr int kL  = kT / kNC;       // 32 steps per chunk
constexpr int LDS_BYTES = 131072;   // 2 bufs x (A 32K + B 32K)

// ---------------------------------------------------------------- helpers
__device__ __forceinline__ void async16(const bf16_t* g, char* l) {
    __builtin_amdgcn_global_load_lds(
        (const __attribute__((address_space(1))) uint32_t*)g,
        (__attribute__((address_space(3))) uint32_t*)l,
        16, 0, 0);
}

// ---------------------------------------------------------------- f32 -> bf16 cast (x)
__global__ void cvt_bf16_kernel(const float* __restrict__ in, bf16_t* __restrict__ out, int n8) {
    int i = blockIdx.x * blockDim.x + threadIdx.x;
    if (i >= n8) return;
    const float4* p = reinterpret_cast<const float4*>(in) + 2 * (size_t)i;
    float4 a = p[0], b = p[1];
    bf16x8 o;
    o[0] = (bf16_t)a.x; o[1] = (bf16_t)a.y; o[2] = (bf16_t)a.z; o[3] = (bf16_t)a.w;
    o[4] = (bf16_t)b.x; o[5] = (bf16_t)b.y; o[6] = (bf16_t)b.z; o[7] = (bf16_t)b.w;
    *reinterpret_cast<bf16x8*>(out + 8 * (size_t)i) = o;
}

// merged cast of the 5 weight matrices (each kD*kD) into contiguous wbf
__global__ void cvtw_kernel(const float* __restrict__ w0, const float* __restrict__ w1,
                            const float* __restrict__ w2, const float* __restrict__ w3,
                            const float* __restrict__ w4, bf16_t* __restrict__ out) {
    const int per = kD * kD / 8;
    int i = blockIdx.x * blockDim.x + threadIdx.x;
    int seg = i / per, j = i - seg * per;
    const float* src = seg == 0 ? w0 : seg == 1 ? w1 : seg == 2 ? w2 : seg == 3 ? w3 : w4;
    const float4* p = reinterpret_cast<const float4*>(src) + 2 * (size_t)j;
    float4 a = p[0], b = p[1];
    bf16x8 o;
    o[0] = (bf16_t)a.x; o[1] = (bf16_t)a.y; o[2] = (bf16_t)a.z; o[3] = (bf16_t)a.w;
    o[4] = (bf16_t)b.x; o[5] = (bf16_t)b.y; o[6] = (bf16_t)b.z; o[7] = (bf16_t)b.w;
    *reinterpret_cast<bf16x8*>(out + ((size_t)seg * per + j) * 8) = o;
}

// ---------------------------------------------------------------- 256x256 BK=64 GEMM
// Minimum-sync K-loop: ONE barrier + ONE (late, ~free) vmcnt(0) per K-tile.
//   top of iter w: stage tile w+1 into buf^1 (its reads finished before the
//   barrier ending iter w-1); then 24 ds_read_b128 + 64 MFMA with no asm in
//   between (compiler emits fine-grained lgkmcnt); then vmcnt(0) -- the stage
//   was issued ~2700cy earlier so the drain is nearly free; then s_barrier.
// 8 waves (2M x 4N), per-wave 128x64 out. st_16x32 XOR swizzle via
// pre-swizzled global source (gload_lds dest linear) + swizzled ds_read.
// EPI: 0 silu->bf16 | 3 f32 nt | 4 slab0 sigmoid->f16 / slab1 sigmoid->bf16 /
//      slab2 tanh->bf16
template<int EPI>
__global__ __launch_bounds__(512, 2)
void gemm256(const bf16_t* __restrict__ A, const bf16_t* __restrict__ Bw,
             const float* __restrict__ bi0, const float* __restrict__ bi1,
             const float* __restrict__ bi2,
             void* __restrict__ out0, void* __restrict__ out1, void* __restrict__ out2,
             int M, int N, int K)
{
    extern __shared__ char lds[];
    const int tid  = threadIdx.x;
    const int lane = tid & 63;
    const int wv   = tid >> 6;
    const int wr   = wv >> 2;      // 0..1  (M waves)
    const int wc   = wv & 3;       // 0..3  (N waves)
    const int l16  = lane & 15;
    const int lhi  = lane >> 4;

    // ---- bijective XCD-chunk swizzle (nwg % 8 == 0 for all our grids) ----
    int bid = blockIdx.y * gridDim.x + blockIdx.x;
    int nwg = gridDim.x * gridDim.y;
    int swz = (bid & 7) * (nwg >> 3) + (bid >> 3);
    int gx  = N >> 8;
    int n0  = (swz % gx) << 8;
    int m0  = (swz / gx) << 8;

    // ---- staging per-thread constants (inverse-swizzled global offsets) ----
    auto goff = [&](int chunk) -> size_t {
        int st = chunk >> 6;               // 1KB subtile
        int ri = (chunk >> 2) & 15;        // inner row
        int cp = (chunk & 3) << 3;         // physical inner col (bf16)
        int cl = cp ^ (((ri >> 3) & 1) << 4);  // logical col (involution)
        int gr = ((st >> 1) << 4) + ri;    // row within 128-row half
        int gc = ((st & 1) << 5) + cl;     // col within BK=64
        return (size_t)gr * K + gc;
    };
    const size_t g0 = goff(tid), g1 = goff(512 + tid);
    const int d0 = wv << 10, d1 = 8192 + (wv << 10);   // linear LDS dest (wave base)

    auto STAGE = [&](const bf16_t* G, int row0, int k0, int lds_base) {
        const bf16_t* base = G + (size_t)row0 * K + k0;
        async16(base + g0, lds + lds_base + d0);
        async16(base + g1, lds + lds_base + d1);
    };
    // stage all 4 half-regions of one K-tile (A lo/hi, B lo/hi) = 8 insts
    auto STAGE_TILE = [&](int w, int bufo) {
        const int k0 = w << 6;
        STAGE(A,  m0,        k0, bufo);
        STAGE(A,  m0 + 128,  k0, bufo + 16384);
        STAGE(Bw, n0,        k0, bufo + 32768);
        STAGE(Bw, n0 + 128,  k0, bufo + 49152);
    };

    // ---- swizzled ds_read offsets (relative to a half-region base) ----
    auto ldsoff = [&](int r, int c) -> int {
        int ri = r & 15;
        int st = ((r >> 4) << 1) | (c >> 5);
        int cw = (c & 31) ^ (((ri >> 3) & 1) << 4);
        return (st << 10) + (ri << 6) + (cw << 1);
    };
    int offA[4][2], offB[2][2];
#pragma unroll
    for (int m = 0; m < 4; ++m)
#pragma unroll
        for (int s = 0; s < 2; ++s)
            offA[m][s] = ldsoff(wr * 64 + m * 16 + l16, s * 32 + lhi * 8);
#pragma unroll
    for (int n = 0; n < 2; ++n)
#pragma unroll
        for (int s = 0; s < 2; ++s)
            offB[n][s] = ldsoff(wc * 32 + n * 16 + l16, s * 32 + lhi * 8);

    f32x4 acc[8][4];
#pragma unroll
    for (int i = 0; i < 8; ++i)
#pragma unroll
        for (int j = 0; j < 4; ++j)
            acc[i][j] = (f32x4){0.f, 0.f, 0.f, 0.f};

    const int NT = K >> 6;   // 16

    // ---- prologue: stage tile 0 only ----
    STAGE_TILE(0, 0);
    asm volatile("s_waitcnt vmcnt(0)" ::: "memory");
    asm volatile("s_barrier" ::: "memory");

    for (int w = 0; w < NT; ++w) {
        const int bufo  = (w & 1) << 16;
        const int nbufo = bufo ^ 65536;
        const int oA0 = bufo, oA1 = bufo + 16384;
        const int oB0 = bufo + 32768, oB1 = bufo + 49152;

        // stage next tile into the buffer whose reads finished last iteration
        if (w + 1 < NT) STAGE_TILE(w + 1, nbufo);

#pragma unroll
        for (int s = 0; s < 2; ++s) {
            bf16x8 aL[4], aH[4], bL[2], bH[2];
#pragma unroll
            for (int m = 0; m < 4; ++m)
                aL[m] = *reinterpret_cast<const bf16x8*>(lds + oA0 + offA[m][s]);
#pragma unroll
            for (int n = 0; n < 2; ++n) {
                bL[n] = *reinterpret_cast<const bf16x8*>(lds + oB0 + offB[n][s]);
                bH[n] = *reinterpret_cast<const bf16x8*>(lds + oB1 + offB[n][s]);
            }
            __builtin_amdgcn_s_setprio(1);
#pragma unroll
            for (int m = 0; m < 4; ++m)
#pragma unroll
                for (int n = 0; n < 2; ++n) {
                    acc[m][n]     = __builtin_amdgcn_mfma_f32_16x16x32_bf16(aL[m], bL[n], acc[m][n], 0, 0, 0);
                    acc[m][2 + n] = __builtin_amdgcn_mfma_f32_16x16x32_bf16(aL[m], bH[n], acc[m][2 + n], 0, 0, 0);
                }
            __builtin_amdgcn_s_setprio(0);
#pragma unroll
            for (int m = 0; m < 4; ++m)
                aH[m] = *reinterpret_cast<const bf16x8*>(lds + oA1 + offA[m][s]);
            __builtin_amdgcn_s_setprio(1);
#pragma unroll
            for (int m = 0; m < 4; ++m)
#pragma unroll
                for (int n = 0; n < 2; ++n) {
                    acc[4 + m][n]     = __builtin_amdgcn_mfma_f32_16x16x32_bf16(aH[m], bL[n], acc[4 + m][n], 0, 0, 0);
                    acc[4 + m][2 + n] = __builtin_amdgcn_mfma_f32_16x16x32_bf16(aH[m], bH[n], acc[4 + m][2 + n], 0, 0, 0);
                }
            __builtin_amdgcn_s_setprio(0);
        }

        if (w + 1 < NT) {
            // stage of tile w+1 was issued ~a full K-tile ago -> drain ~free
            asm volatile("s_waitcnt vmcnt(0)" ::: "memory");
            asm volatile("s_barrier" ::: "memory");
        }
    }

    // ---- epilogue: C/D layout col=lane&15, row=(lane>>4)*4+r ----
    const int slab = n0 >> 10;                 // block-uniform (EPI==4)
    const float* bia = (EPI == 4) ? (slab == 0 ? bi0 : slab == 1 ? bi1 : bi2) : nullptr;
#pragma unroll
    for (int j = 0; j < 4; ++j) {
        const int colg = n0 + ((j >> 1) << 7) + wc * 32 + (j & 1) * 16 + l16;
        const int cL = colg & (kD - 1);
        float bs = 0.f;
        if constexpr (EPI == 4) bs = bia[cL];
#pragma unroll
        for (int i = 0; i < 8; ++i) {
            const int rb = m0 + ((i >> 2) << 7) + wr * 64 + (i & 3) * 16 + lhi * 4;
#pragma unroll
            for (int r = 0; r < 4; ++r) {
                const int rowg = rb + r;
                const float f = acc[i][j][r];
                if constexpr (EPI == 0) {
                    float s = f / (1.f + __expf(-f));
                    reinterpret_cast<bf16_t*>(out0)[(size_t)rowg * N + colg] = (bf16_t)s;
                } else if constexpr (EPI == 3) {
                    __builtin_nontemporal_store(f, reinterpret_cast<float*>(out0) + (size_t)rowg * N + colg);
                } else {  // EPI == 4
                    const size_t idx = (size_t)rowg * kD + cL;
                    if (slab == 0) {
                        float s = 1.f / (1.f + __expf(-(f + bs)));
                        __builtin_nontemporal_store((f16_t)s, reinterpret_cast<f16_t*>(out0) + idx);
                    } else if (slab == 1) {
                        float s = 1.f / (1.f + __expf(-(f + bs)));
                        __builtin_nontemporal_store((bf16_t)s, reinterpret_cast<bf16_t*>(out1) + idx);
                    } else {
                        float s = tanhf(f + bs);
                        __builtin_nontemporal_store((bf16_t)s, reinterpret_cast<bf16_t*>(out2) + idx);
                    }
                }
            }
        }
    }
}

// ---------------------------------------------------------------- chunked linear scan
// h_t = a_t*h + beta_t*v_t ; alpha fp16, beta/v bf16.
__global__ void scan_chunk_kernel(const f16_t* __restrict__ alpha,
                                  const bf16_t* __restrict__ beta,
                                  const bf16_t* __restrict__ vv,
                                  float* __restrict__ Aagg,
                                  float* __restrict__ Bagg)
{
    const int u  = blockIdx.x * blockDim.x + threadIdx.x;
    const int ch = u & (kCH - 1);
    const int c  = u >> 12;
    const int b  = ch >> 10;
    const int d  = ch & (kD - 1);
    size_t base = ((size_t)b * kT + (size_t)c * kL) * kD + d;
    float Ac = 1.f, Bc = 0.f;
#pragma unroll 4
    for (int t = 0; t < kL; ++t) {
        float a  = (float)alpha[base];
        float bv = (float)beta[base] * (float)vv[base];
        Ac *= a;
        Bc = a * Bc + bv;
        base += kD;
    }
    Aagg[u] = Ac;
    Bagg[u] = Bc;
}

__global__ void scan_mid_kernel(const float* __restrict__ Aagg,
                                const float* __restrict__ Bagg,
                                float* __restrict__ Hin,
                                float* __restrict__ hlast)
{
    const int ch = blockIdx.x * blockDim.x + threadIdx.x;
    float h = 0.f;
#pragma unroll 8
    for (int c = 0; c < kNC; ++c) {
        Hin[(size_t)c * kCH + ch] = h;
        h = Aagg[(size_t)c * kCH + ch] * h + Bagg[(size_t)c * kCH + ch];
    }
    hlast[ch] = h;
}

__global__ void scan_out_kernel(const f16_t* __restrict__ alpha,
                                const bf16_t* __restrict__ beta,
                                const bf16_t* __restrict__ vv,
                                const float* __restrict__ Hin,
                                bf16_t* __restrict__ cell)
{
    const int u  = blockIdx.x * blockDim.x + threadIdx.x;
    const int ch = u & (kCH - 1);
    const int c  = u >> 12;
    const int b  = ch >> 10;
    const int d  = ch & (kD - 1);
    size_t base = ((size_t)b * kT + (size_t)c * kL) * kD + d;
    float h = Hin[u];
#pragma unroll 4
    for (int t = 0; t < kL; ++t) {
        float a  = (float)alpha[base];
        float bv = (float)beta[base] * (float)vv[base];
        h = a * h + bv;
        float s = 1.f / (1.f + __expf(-h));
        cell[base] = (bf16_t)(h * h * s);
        base += kD;
    }
}

// ---------------------------------------------------------------- launch
extern "C" void kernel_launch(void* const* d_in, const int* in_sizes, int n_in,
                              void* d_out, int out_size, void* d_ws, size_t ws_size,
                              hipStream_t stream)
{
    const float* x     = (const float*)d_in[0];
    const float* W_in  = (const float*)d_in[1];
    const float* W_al  = (const float*)d_in[2];
    const float* b_al  = (const float*)d_in[3];
    const float* W_be  = (const float*)d_in[4];
    const float* b_be  = (const float*)d_in[5];
    const float* W_v   = (const float*)d_in[6];
    const float* b_v   = (const float*)d_in[7];
    const float* W_out = (const float*)d_in[8];

    float* out   = (float*)d_out;
    float* hlast = out + (size_t)kM * kD;

    char* ws = (char*)d_ws;
    size_t off = 0;
    auto alloc = [&](size_t bytes) -> void* {
        void* p = ws + off;
        off += (bytes + 255) & ~(size_t)255;
        return p;
    };
    bf16_t* xbf   = (bf16_t*)alloc((size_t)kM * kD * 2);   // dead after GEMM1 -> cell
    bf16_t* xp    = (bf16_t*)alloc((size_t)kM * kD * 2);   // dead after fused -> aggs
    f16_t*  alpha = (f16_t*) alloc((size_t)kM * kD * 2);
    bf16_t* betab = (bf16_t*)alloc((size_t)kM * kD * 2);
    bf16_t* vb    = (bf16_t*)alloc((size_t)kM * kD * 2);
    bf16_t* wbf   = (bf16_t*)alloc((size_t)5 * kD * kD * 2);

    bf16_t* Winb = wbf;                         // [W_in; W_al; W_be; W_v; W_out]
    bf16_t* Wfus = wbf + 1 * (size_t)kD * kD;   // fused B: rows 0..3071
    bf16_t* Wob  = wbf + 4 * (size_t)kD * kD;

    bf16_t* cell = xbf;
    float*  Aagg = (float*)xp;
    float*  Bagg = Aagg + (size_t)kNC * kCH;
    float*  Hin  = Bagg + (size_t)kNC * kCH;

    hipFuncSetAttribute(reinterpret_cast<const void*>(gemm256<0>), hipFuncAttributeMaxDynamicSharedMemorySize, LDS_BYTES);
    hipFuncSetAttribute(reinterpret_cast<const void*>(gemm256<3>), hipFuncAttributeMaxDynamicSharedMemorySize, LDS_BYTES);
    hipFuncSetAttribute(reinterpret_cast<const void*>(gemm256<4>), hipFuncAttributeMaxDynamicSharedMemorySize, LDS_BYTES);

    // 1) casts to bf16
    {
        int n8 = kM * kD / 8;
        cvt_bf16_kernel<<<(n8 + 255) / 256, 256, 0, stream>>>(x, xbf, n8);
        int wtot = 5 * kD * kD / 8;
        cvtw_kernel<<<(wtot + 255) / 256, 256, 0, stream>>>(W_in, W_al, W_be, W_v, W_out, wbf);
    }

    dim3 grid1(kD / 256, kM / 256);     // (4, 64)  = 256 wgs
    dim3 gridF(3 * kD / 256, kM / 256); // (12, 64) = 768 wgs

    // 2) xp = silu(x @ W_in^T)                       [bf16]
    gemm256<0><<<grid1, 512, LDS_BYTES, stream>>>(xbf, Winb, nullptr, nullptr, nullptr,
                                                  xp, nullptr, nullptr, kM, kD, kD);
    // 3) fused: alpha=sigmoid(+b_al) f16 | beta=sigmoid(+b_be) bf16 | v=tanh(+b_v) bf16
    gemm256<4><<<gridF, 512, LDS_BYTES, stream>>>(xp, Wfus, b_al, b_be, b_v,
                                                  alpha, betab, vb, kM, 3 * kD, kD);
    // 4) chunked scan (bv = beta*v on the fly)
    scan_chunk_kernel<<<kNC * kCH / 256, 256, 0, stream>>>(alpha, betab, vb, Aagg, Bagg);
    scan_mid_kernel<<<kCH / 256, 256, 0, stream>>>(Aagg, Bagg, Hin, hlast);
    scan_out_kernel<<<kNC * kCH / 256, 256, 0, stream>>>(alpha, betab, vb, Hin, cell);

    // 5) output = cell @ W_out^T                     [f32 nt -> d_out]
    gemm256<3><<<grid1, 512, LDS_BYTES, stream>>>(cell, Wob, nullptr, nullptr, nullptr,
                                                  out, nullptr, nullptr, kM, kD, kD);
}